// Round 1
// baseline (401.541 us; speedup 1.0000x reference)
//
#include <hip/hip_runtime.h>
#include <math.h>

#define NCLS 80
#define NANC 18
#define NB 8
#define GG 76
#define SS (GG*GG)              // 5776
#define CHN (NCLS+6)            // 86
#define NCELL (NB*NANC*SS)      // 831744
#define FLAG_WORDS ((NCELL+31)/32)  // 25992
#define NT_MAX 240
#define TILE 64
#define NTILES ((SS+TILE-1)/TILE)   // 91
#define PI_ 3.14159265358979323846

// MASKED_ANCHORS: [w/8, h/8, angle] ; anchors outer, angles inner
__device__ __constant__ float d_ma[NANC][3] = {
  {1.5f, 2.0f, (float)(-PI_/3)}, {1.5f, 2.0f, (float)(-PI_/6)}, {1.5f, 2.0f, 0.0f},
  {1.5f, 2.0f, (float)(PI_/6)},  {1.5f, 2.0f, (float)(PI_/3)},  {1.5f, 2.0f, (float)(PI_/2)},
  {2.375f, 4.5f, (float)(-PI_/3)}, {2.375f, 4.5f, (float)(-PI_/6)}, {2.375f, 4.5f, 0.0f},
  {2.375f, 4.5f, (float)(PI_/6)},  {2.375f, 4.5f, (float)(PI_/3)},  {2.375f, 4.5f, (float)(PI_/2)},
  {5.0f, 3.5f, (float)(-PI_/3)}, {5.0f, 3.5f, (float)(-PI_/6)}, {5.0f, 3.5f, 0.0f},
  {5.0f, 3.5f, (float)(PI_/6)},  {5.0f, 3.5f, (float)(PI_/3)},  {5.0f, 3.5f, (float)(PI_/2)},
};

__device__ __forceinline__ float sigm(float x) { return 1.0f / (1.0f + expf(-x)); }

// ---------------- K0: zero workspace words ----------------
__global__ void k_zero(unsigned* __restrict__ w, int n) {
  int i = blockIdx.x * blockDim.x + threadIdx.x;
  if (i < n) w[i] = 0u;
}

// ---------------- K1: per-target prep + scatter + per-winner loss ----------------
__global__ __launch_bounds__(256) void k_prep(const float* __restrict__ tgt,
                                              const float* __restrict__ in,
                                              unsigned* __restrict__ flags,
                                              double* __restrict__ acc,
                                              int* __restrict__ cnt, int nT) {
  __shared__ int s_key[NT_MAX], s_lab[NT_MAX], s_bn[NT_MAX], s_bi[NT_MAX], s_gi[NT_MAX], s_gj[NT_MAX];
  __shared__ unsigned s_cond[NT_MAX];
  __shared__ float s_tb[NT_MAX][5];
  __shared__ double s_reg[NT_MAX], s_fl1[NT_MAX], s_cls[NT_MAX];
  __shared__ int s_win[NT_MAX];
  __shared__ int s_zero;

  int t = threadIdx.x;
  if (t == 0) s_zero = 0;
  if (t < nT) {
    float bf = tgt[t*7+0], lf = tgt[t*7+1];
    float gx = tgt[t*7+2] * (float)GG, gy = tgt[t*7+3] * (float)GG;
    float gw = tgt[t*7+4] * (float)GG, gh = tgt[t*7+5] * (float)GG;
    float ga = tgt[t*7+6];
    int bi = (int)bf, lab = (int)lf, gi = (int)gx, gj = (int)gy;
    float best = -1e30f; int bn = 0; unsigned cm = 0;
    for (int a = 0; a < NANC; ++a) {
      float aw = d_ma[a][0], ah = d_ma[a][1], aa = d_ma[a][2];
      float inter = fminf(aw, gw) * fminf(ah, gh);
      float uni = aw*ah + 1e-16f + gw*gh - inter;
      float off = fabsf(aa - ga);
      float ar = inter / uni * fabsf(cosf(aa - ga));
      if (ar > best) { best = ar; bn = a; }          // first-max wins (strict >)
      if (ar > 0.5f || (ar > 0.4f && off < (float)(PI_/12))) cm |= (1u << a);
    }
    s_key[t] = ((bi*NANC + bn)*GG + gj)*GG + gi;
    s_lab[t] = lab; s_bn[t] = bn; s_bi[t] = bi; s_gi[t] = gi; s_gj[t] = gj;
    s_cond[t] = cm;
    s_tb[t][0] = gx; s_tb[t][1] = gy; s_tb[t][2] = gw; s_tb[t][3] = gh; s_tb[t][4] = ga;
    s_reg[t] = 0.0; s_fl1[t] = 0.0; s_cls[t] = 0.0; s_win[t] = 0;
  }
  __syncthreads();

  if (t < nT) {
    int bi = s_bi[t], gi = s_gi[t], gj = s_gj[t], bn = s_bn[t];
    unsigned cm = s_cond[t];
    // scatter noobj-zero bits: cond anchors + best anchor
    for (int a = 0; a < NANC; ++a) {
      if (((cm >> a) & 1u) || a == bn) {
        int cell = ((bi*NANC + a)*GG + gj)*GG + gi;
        unsigned bit = 1u << (cell & 31);
        unsigned old = atomicOr(&flags[cell >> 5], bit);
        if (!(old & bit)) atomicAdd(&s_zero, 1);
      }
    }
    // winner = last target (max index) with this cell key  (numpy last-write-wins)
    int key = s_key[t];
    bool winner = true;
    for (int t2 = t + 1; t2 < nT; ++t2) if (s_key[t2] == key) { winner = false; break; }
    if (winner) {
      s_win[t] = 1;
      // label union at this cell (tcls set per-target incl. losers)
      unsigned long long lm0 = 0, lm1 = 0;
      for (int t2 = 0; t2 < nT; ++t2) if (s_key[t2] == key) {
        int L = s_lab[t2];
        if (L < 64) lm0 |= 1ull << L; else lm1 |= 1ull << (L - 64);
      }
      const float* base = in + ((size_t)bi*(NANC*CHN) + (size_t)bn*CHN)*SS + (size_t)gj*GG + gi;
      float rx = base[0], ry = base[(size_t)SS], rw = base[2*(size_t)SS],
            rh = base[3*(size_t)SS], ra = base[4*(size_t)SS], rcf = base[5*(size_t)SS];
      float aw = d_ma[bn][0], ah = d_ma[bn][1], aa = d_ma[bn][2];
      float px = sigm(rx)*1.05f - 0.025f + (float)gi;
      float py = sigm(ry)*1.05f - 0.025f + (float)gj;
      float pw = expf(rw)*aw, ph = expf(rh)*ah;
      float pang = ra + aa;
      float gx = s_tb[t][0], gyv = s_tb[t][1], gw = s_tb[t][2], gh = s_tb[t][3], ga = s_tb[t][4];
      // CIoU (follow reference literally)
      float p1x = px - pw*0.5f, p1y = py - ph*0.5f, p2x = px + pw*0.5f, p2y = py + ph*0.5f;
      float t1x = gx - gw*0.5f, t1y = gyv - gh*0.5f, t2x = gx + gw*0.5f, t2y = gyv + gh*0.5f;
      float w1 = p2x - p1x, h1 = p2y - p1y, w2 = t2x - t1x, h2 = t2y - t1y;
      float area1 = w1*h1, area2 = w2*h2;
      float c1x = (p1x+p2x)*0.5f, c1y = (p1y+p2y)*0.5f, c2x = (t1x+t2x)*0.5f, c2y = (t1y+t2y)*0.5f;
      float ix = fmaxf(fminf(p2x,t2x) - fmaxf(p1x,t1x), 0.0f);
      float iy = fmaxf(fminf(p2y,t2y) - fmaxf(p1y,t1y), 0.0f);
      float inter_area = ix*iy;
      float dcx = c2x - c1x, dcy = c2y - c1y;
      float inter_diag = dcx*dcx + dcy*dcy;
      float ox = fmaxf(fmaxf(p2x,t2x) - fminf(p1x,t1x), 0.0f);
      float oy = fmaxf(fmaxf(p2y,t2y) - fminf(p1y,t1y), 0.0f);
      float outer_diag = ox*ox + oy*oy;
      float uni = area1 + area2 - inter_area;
      float u = inter_diag / outer_diag;
      float iou = inter_area / uni;
      float da = atanf(w2/h2) - atanf(w1/h1);
      float v = (float)(4.0/(PI_*PI_)) * da * da;
      float alpha = v / (1.0f - iou + v);
      float ciou = fminf(fmaxf(iou - (u + alpha*v), -1.0f), 1.0f);
      float skew_iou = iou * fabsf(cosf(pang - ga));
      float skew = expf(1.0f - skew_iou) - 1.0f;
      float bscale = 2.0f - gw*gh/369664.0f;   // (8*76)^2
      float ciou_t = bscale * (1.0f - ciou);
      float ta = ga - aa;
      float d = fabsf(ra - ta);
      float sl1 = (d < 1.0f) ? 0.5f*d*d : d - 0.5f;
      float reg = sl1 + ciou_t;
      float rcn = skew / reg;                  // reg_const, as written
      s_reg[t] = (double)(reg * rcn);
      // focal(pconf, 1): bce uses clipped p, p_t uses raw p
      float pc = sigm(rcf);
      float pcl = fminf(fmaxf(pc, 1e-7f), 1.0f - 1e-7f);
      float om = 1.0f - pc;
      s_fl1[t] = (double)(-logf(pcl) * 0.25f * om * om);
      // cls bce vs label-union one-hot
      float csum = 0.0f;
      for (int c = 0; c < NCLS; ++c) {
        float p = sigm(base[(size_t)(6 + c)*SS]);
        float pl = fminf(fmaxf(p, 1e-7f), 1.0f - 1e-7f);
        bool tc = (c < 64) ? ((lm0 >> c) & 1ull) : ((lm1 >> (c - 64)) & 1ull);
        csum += tc ? -logf(pl) : -logf(1.0f - pl);
      }
      s_cls[t] = (double)csum;
    }
  }
  __syncthreads();
  if (t == 0) {
    double r = 0, f1 = 0, cl = 0; int nw = 0;
    for (int i = 0; i < nT; ++i) { r += s_reg[i]; f1 += s_fl1[i]; cl += s_cls[i]; nw += s_win[i]; }
    acc[1] = f1; acc[2] = r; acc[3] = cl;
    cnt[0] = s_zero; cnt[1] = nw;
  }
}

// ---------------- K2: big transpose/decode pass + noobj focal reduction ----------------
__global__ __launch_bounds__(256) void k_main(const float* __restrict__ in,
                                              float* __restrict__ out,
                                              const unsigned* __restrict__ flags,
                                              double* __restrict__ acc) {
  __shared__ float lds[CHN * 65];
  __shared__ double wsum[4];
  int blk = blockIdx.x;
  int tile = blk % NTILES;
  int ba = blk / NTILES;
  int a = ba % NANC, b = ba / NANC;
  int s0 = tile * TILE;
  int count = min(TILE, SS - s0);

  const float* inb = in + ((size_t)b*(NANC*CHN) + (size_t)a*CHN)*SS + s0;
  for (int i = threadIdx.x; i < CHN*TILE; i += 256) {
    int c = i >> 6, s = i & 63;
    if (s < count) lds[c*65 + s] = inb[(size_t)c*SS + s];
  }
  __syncthreads();

  float aw = d_ma[a][0], ah = d_ma[a][1], aa = d_ma[a][2];
  double fl0 = 0.0;
  float* outb = out + ((size_t)b*(NANC*SS) + (size_t)a*SS + s0)*CHN;
  for (int i = threadIdx.x; i < count*CHN; i += 256) {
    int s = i / CHN, c = i - s*CHN;
    float v = lds[c*65 + s];
    int spos = s0 + s;
    float r;
    if (c == 0)      { int gx = spos % GG; r = (sigm(v)*1.05f - 0.025f + (float)gx) * 8.0f; }
    else if (c == 1) { int gy = spos / GG; r = (sigm(v)*1.05f - 0.025f + (float)gy) * 8.0f; }
    else if (c == 2) r = expf(v) * aw * 8.0f;
    else if (c == 3) r = expf(v) * ah * 8.0f;
    else if (c == 4) r = v + aa;
    else {
      float p = sigm(v);
      r = p;
      if (c == 5) {
        int cell = (b*NANC + a)*SS + spos;
        if (!((flags[cell >> 5] >> (cell & 31)) & 1u)) {
          float pcl = fminf(fmaxf(p, 1e-7f), 1.0f - 1e-7f);
          fl0 += (double)(-logf(1.0f - pcl) * 0.75f * p * p);
        }
      }
    }
    outb[i] = r;
  }
  // block-reduce fl0 (double) then one atomicAdd per block
  int lane = threadIdx.x & 63, wid = threadIdx.x >> 6;
  for (int off = 32; off > 0; off >>= 1) fl0 += __shfl_down(fl0, off);
  if (lane == 0) wsum[wid] = fl0;
  __syncthreads();
  if (threadIdx.x == 0) atomicAdd(&acc[0], wsum[0] + wsum[1] + wsum[2] + wsum[3]);
}

// ---------------- K3: finalize loss ----------------
__global__ void k_fin(const double* __restrict__ acc, const int* __restrict__ cnt,
                      float* __restrict__ out) {
  double n_obj = fmax((double)cnt[1], 1.0);
  double n_noobj = fmax((double)(NCELL - cnt[0]), 1.0);
  double reg_loss = acc[2] / n_obj;
  double conf_loss = acc[1] / n_obj + acc[0] / n_noobj;
  double cls_loss = acc[3] / (n_obj * (double)NCLS);
  out[(size_t)NCELL * CHN] = (float)(reg_loss + 10.0*conf_loss + cls_loss);
}

extern "C" void kernel_launch(void* const* d_in, const int* in_sizes, int n_in,
                              void* d_out, int out_size, void* d_ws, size_t ws_size,
                              hipStream_t stream) {
  const float* in  = (const float*)d_in[0];
  const float* tgt = (const float*)d_in[1];
  float* out = (float*)d_out;
  double* acc = (double*)d_ws;                       // 4 doubles
  int* cnt = (int*)((char*)d_ws + 32);               // 2 ints
  unsigned* flags = (unsigned*)((char*)d_ws + 64);   // FLAG_WORDS words
  int nT = in_sizes[1] / 7;
  if (nT > NT_MAX) nT = NT_MAX;

  int nzw = 16 + FLAG_WORDS;                         // words to zero (acc+cnt+flags)
  hipLaunchKernelGGL(k_zero, dim3((nzw + 255)/256), dim3(256), 0, stream,
                     (unsigned*)d_ws, nzw);
  hipLaunchKernelGGL(k_prep, dim3(1), dim3(256), 0, stream, tgt, in, flags, acc, cnt, nT);
  hipLaunchKernelGGL(k_main, dim3(NB*NANC*NTILES), dim3(256), 0, stream, in, out, flags, acc);
  hipLaunchKernelGGL(k_fin, dim3(1), dim3(1), 0, stream, acc, cnt, out);
}

// Round 2
// 341.979 us; speedup vs baseline: 1.1742x; 1.1742x over previous
//
#include <hip/hip_runtime.h>
#include <math.h>

#define NCLS 80
#define NANC 18
#define NB 8
#define GG 76
#define SS (GG*GG)              // 5776
#define CHN (NCLS+6)            // 86
#define NCELL (NB*NANC*SS)      // 831744
#define FLAG_WORDS ((NCELL+31)/32)  // 25992
#define NT_MAX 240
#define TILE 64
#define NTILES ((SS+TILE-1)/TILE)   // 91
#define PI_ 3.14159265358979323846

// MASKED_ANCHORS: [w/8, h/8, angle] ; anchors outer, angles inner
__device__ __constant__ float d_ma[NANC][3] = {
  {1.5f, 2.0f, (float)(-PI_/3)}, {1.5f, 2.0f, (float)(-PI_/6)}, {1.5f, 2.0f, 0.0f},
  {1.5f, 2.0f, (float)(PI_/6)},  {1.5f, 2.0f, (float)(PI_/3)},  {1.5f, 2.0f, (float)(PI_/2)},
  {2.375f, 4.5f, (float)(-PI_/3)}, {2.375f, 4.5f, (float)(-PI_/6)}, {2.375f, 4.5f, 0.0f},
  {2.375f, 4.5f, (float)(PI_/6)},  {2.375f, 4.5f, (float)(PI_/3)},  {2.375f, 4.5f, (float)(PI_/2)},
  {5.0f, 3.5f, (float)(-PI_/3)}, {5.0f, 3.5f, (float)(-PI_/6)}, {5.0f, 3.5f, 0.0f},
  {5.0f, 3.5f, (float)(PI_/6)},  {5.0f, 3.5f, (float)(PI_/3)},  {5.0f, 3.5f, (float)(PI_/2)},
};

// precise sigmoid (k_prep argmax-adjacent paths don't use it; fine to be fast everywhere,
// but keep a precise one available)
__device__ __forceinline__ float sigm(float x) { return 1.0f / (1.0f + expf(-x)); }
// fast sigmoid: v_exp_f32 + v_rcp_f32 (~1 ulp each)
__device__ __forceinline__ float fsig(float x) {
  return __builtin_amdgcn_rcpf(1.0f + __expf(-x));
}

// ---------------- K0: zero workspace words ----------------
__global__ void k_zero(unsigned* __restrict__ w, int n) {
  int i = blockIdx.x * blockDim.x + threadIdx.x;
  if (i < n) w[i] = 0u;
}

// ---------------- K1: per-target prep + scatter + per-winner loss ----------------
__global__ __launch_bounds__(256) void k_prep(const float* __restrict__ tgt,
                                              const float* __restrict__ in,
                                              unsigned* __restrict__ flags,
                                              double* __restrict__ acc,
                                              int* __restrict__ cnt, int nT) {
  __shared__ int s_key[NT_MAX], s_lab[NT_MAX], s_bn[NT_MAX], s_bi[NT_MAX], s_gi[NT_MAX], s_gj[NT_MAX];
  __shared__ unsigned s_cond[NT_MAX];
  __shared__ float s_tb[NT_MAX][5];
  __shared__ double s_reg[NT_MAX], s_fl1[NT_MAX], s_cls[NT_MAX];
  __shared__ int s_win[NT_MAX];
  __shared__ int s_zero;

  int t = threadIdx.x;
  if (t == 0) s_zero = 0;
  if (t < nT) {
    float bf = tgt[t*7+0], lf = tgt[t*7+1];
    float gx = tgt[t*7+2] * (float)GG, gy = tgt[t*7+3] * (float)GG;
    float gw = tgt[t*7+4] * (float)GG, gh = tgt[t*7+5] * (float)GG;
    float ga = tgt[t*7+6];
    int bi = (int)bf, lab = (int)lf, gi = (int)gx, gj = (int)gy;
    float best = -1e30f; int bn = 0; unsigned cm = 0;
    for (int a = 0; a < NANC; ++a) {
      float aw = d_ma[a][0], ah = d_ma[a][1], aa = d_ma[a][2];
      float inter = fminf(aw, gw) * fminf(ah, gh);
      float uni = aw*ah + 1e-16f + gw*gh - inter;
      float off = fabsf(aa - ga);
      float ar = inter / uni * fabsf(cosf(aa - ga));   // precise cosf: argmax stability
      if (ar > best) { best = ar; bn = a; }            // first-max wins (strict >)
      if (ar > 0.5f || (ar > 0.4f && off < (float)(PI_/12))) cm |= (1u << a);
    }
    s_key[t] = ((bi*NANC + bn)*GG + gj)*GG + gi;
    s_lab[t] = lab; s_bn[t] = bn; s_bi[t] = bi; s_gi[t] = gi; s_gj[t] = gj;
    s_cond[t] = cm;
    s_tb[t][0] = gx; s_tb[t][1] = gy; s_tb[t][2] = gw; s_tb[t][3] = gh; s_tb[t][4] = ga;
    s_reg[t] = 0.0; s_fl1[t] = 0.0; s_cls[t] = 0.0; s_win[t] = 0;
  }
  __syncthreads();

  if (t < nT) {
    int bi = s_bi[t], gi = s_gi[t], gj = s_gj[t], bn = s_bn[t];
    unsigned cm = s_cond[t];
    // scatter noobj-zero bits: cond anchors + best anchor
    for (int a = 0; a < NANC; ++a) {
      if (((cm >> a) & 1u) || a == bn) {
        int cell = ((bi*NANC + a)*GG + gj)*GG + gi;
        unsigned bit = 1u << (cell & 31);
        unsigned old = atomicOr(&flags[cell >> 5], bit);
        if (!(old & bit)) atomicAdd(&s_zero, 1);
      }
    }
    // winner = last target (max index) with this cell key  (numpy last-write-wins)
    int key = s_key[t];
    bool winner = true;
    for (int t2 = t + 1; t2 < nT; ++t2) if (s_key[t2] == key) { winner = false; break; }
    if (winner) {
      s_win[t] = 1;
      // label union at this cell (tcls set per-target incl. losers)
      unsigned long long lm0 = 0, lm1 = 0;
      for (int t2 = 0; t2 < nT; ++t2) if (s_key[t2] == key) {
        int L = s_lab[t2];
        if (L < 64) lm0 |= 1ull << L; else lm1 |= 1ull << (L - 64);
      }
      const float* base = in + ((size_t)bi*(NANC*CHN) + (size_t)bn*CHN)*SS + (size_t)gj*GG + gi;
      float rx = base[0], ry = base[(size_t)SS], rw = base[2*(size_t)SS],
            rh = base[3*(size_t)SS], ra = base[4*(size_t)SS], rcf = base[5*(size_t)SS];
      float aw = d_ma[bn][0], ah = d_ma[bn][1], aa = d_ma[bn][2];
      float px = sigm(rx)*1.05f - 0.025f + (float)gi;
      float py = sigm(ry)*1.05f - 0.025f + (float)gj;
      float pw = expf(rw)*aw, ph = expf(rh)*ah;
      float pang = ra + aa;
      float gx = s_tb[t][0], gyv = s_tb[t][1], gw = s_tb[t][2], gh = s_tb[t][3], ga = s_tb[t][4];
      // CIoU (follow reference literally)
      float p1x = px - pw*0.5f, p1y = py - ph*0.5f, p2x = px + pw*0.5f, p2y = py + ph*0.5f;
      float t1x = gx - gw*0.5f, t1y = gyv - gh*0.5f, t2x = gx + gw*0.5f, t2y = gyv + gh*0.5f;
      float w1 = p2x - p1x, h1 = p2y - p1y, w2 = t2x - t1x, h2 = t2y - t1y;
      float area1 = w1*h1, area2 = w2*h2;
      float c1x = (p1x+p2x)*0.5f, c1y = (p1y+p2y)*0.5f, c2x = (t1x+t2x)*0.5f, c2y = (t1y+t2y)*0.5f;
      float ix = fmaxf(fminf(p2x,t2x) - fmaxf(p1x,t1x), 0.0f);
      float iy = fmaxf(fminf(p2y,t2y) - fmaxf(p1y,t1y), 0.0f);
      float inter_area = ix*iy;
      float dcx = c2x - c1x, dcy = c2y - c1y;
      float inter_diag = dcx*dcx + dcy*dcy;
      float ox = fmaxf(fmaxf(p2x,t2x) - fminf(p1x,t1x), 0.0f);
      float oy = fmaxf(fmaxf(p2y,t2y) - fminf(p1y,t1y), 0.0f);
      float outer_diag = ox*ox + oy*oy;
      float uni = area1 + area2 - inter_area;
      float u = inter_diag / outer_diag;
      float iou = inter_area / uni;
      float da = atanf(w2/h2) - atanf(w1/h1);
      float v = (float)(4.0/(PI_*PI_)) * da * da;
      float alpha = v / (1.0f - iou + v);
      float ciou = fminf(fmaxf(iou - (u + alpha*v), -1.0f), 1.0f);
      float skew_iou = iou * fabsf(cosf(pang - ga));
      float skew = expf(1.0f - skew_iou) - 1.0f;
      float bscale = 2.0f - gw*gh/369664.0f;   // (8*76)^2
      float ciou_t = bscale * (1.0f - ciou);
      float ta = ga - aa;
      float d = fabsf(ra - ta);
      float sl1 = (d < 1.0f) ? 0.5f*d*d : d - 0.5f;
      float reg = sl1 + ciou_t;
      float rcn = skew / reg;                  // reg_const, as written
      s_reg[t] = (double)(reg * rcn);
      // focal(pconf, 1): bce uses clipped p, p_t uses raw p
      float pc = sigm(rcf);
      float pcl = fminf(fmaxf(pc, 1e-7f), 1.0f - 1e-7f);
      float om = 1.0f - pc;
      s_fl1[t] = (double)(-logf(pcl) * 0.25f * om * om);
      // cls bce vs label-union one-hot (hot loop: native exp/log)
      float csum = 0.0f;
      for (int c = 0; c < NCLS; ++c) {
        float p = fsig(base[(size_t)(6 + c)*SS]);
        float pl = fminf(fmaxf(p, 1e-7f), 1.0f - 1e-7f);
        bool tc = (c < 64) ? ((lm0 >> c) & 1ull) : ((lm1 >> (c - 64)) & 1ull);
        csum += tc ? -__logf(pl) : -__logf(1.0f - pl);
      }
      s_cls[t] = (double)csum;
    }
  }
  __syncthreads();
  if (t == 0) {
    double r = 0, f1 = 0, cl = 0; int nw = 0;
    for (int i = 0; i < nT; ++i) { r += s_reg[i]; f1 += s_fl1[i]; cl += s_cls[i]; nw += s_win[i]; }
    acc[1] = f1; acc[2] = r; acc[3] = cl;
    cnt[0] = s_zero; cnt[1] = nw;
  }
}

// ---------------- K2: big transpose/decode pass + noobj focal reduction ----------------
// Two divergence-free passes: (B) 5 box channels, one lane per spatial cell;
// (A) 81 sigmoid channels (conf+cls), uniform op across lanes, j==0 folds noobj focal.
__global__ __launch_bounds__(256) void k_main(const float* __restrict__ in,
                                              float* __restrict__ out,
                                              const unsigned* __restrict__ flags,
                                              double* __restrict__ acc) {
  __shared__ float lds[CHN * 65];
  __shared__ double wsum[4];
  int blk = blockIdx.x;
  int tile = blk % NTILES;
  int ba = blk / NTILES;
  int a = ba % NANC, b = ba / NANC;
  int s0 = tile * TILE;
  int count = min(TILE, SS - s0);

  const float* inb = in + ((size_t)b*(NANC*CHN) + (size_t)a*CHN)*SS + s0;
  for (int i = threadIdx.x; i < CHN*TILE; i += 256) {
    int c = i >> 6, s = i & 63;
    if (s < count) lds[c*65 + s] = inb[(size_t)c*SS + s];
  }
  __syncthreads();

  float aw = d_ma[a][0], ah = d_ma[a][1], aa = d_ma[a][2];
  float* outb = out + ((size_t)b*(NANC*SS) + (size_t)a*SS + s0)*CHN;

  // ---- Pass B: channels 0..4, one lane per spatial cell ----
  if (threadIdx.x < count) {
    int s = threadIdx.x;
    int spos = s0 + s;
    int gx = spos % GG, gy = spos / GG;
    float* o = outb + s*CHN;
    o[0] = (fsig(lds[0*65 + s])*1.05f - 0.025f + (float)gx) * 8.0f;
    o[1] = (fsig(lds[1*65 + s])*1.05f - 0.025f + (float)gy) * 8.0f;
    o[2] = __expf(lds[2*65 + s]) * aw * 8.0f;
    o[3] = __expf(lds[3*65 + s]) * ah * 8.0f;
    o[4] = lds[4*65 + s] + aa;
  }

  // ---- Pass A: channels 5..85 (conf + 80 classes), uniform sigmoid ----
  double fl0 = 0.0;
  int cellbase = (b*NANC + a)*SS + s0;
  for (int i = threadIdx.x; i < count*81; i += 256) {
    int s = i / 81;                 // magic-mul div (constexpr)
    int j = i - s*81;               // channel = 5 + j
    float v = lds[(5 + j)*65 + s];
    float p = fsig(v);
    if (j == 0) {
      int cell = cellbase + s;
      if (!((flags[cell >> 5] >> (cell & 31)) & 1u)) {
        float pcl = fminf(fmaxf(p, 1e-7f), 1.0f - 1e-7f);
        fl0 += (double)(-__logf(1.0f - pcl) * 0.75f * p * p);
      }
    }
    outb[s*CHN + 5 + j] = p;
  }

  // block-reduce fl0 (double) then one atomicAdd per block
  int lane = threadIdx.x & 63, wid = threadIdx.x >> 6;
  for (int off = 32; off > 0; off >>= 1) fl0 += __shfl_down(fl0, off);
  if (lane == 0) wsum[wid] = fl0;
  __syncthreads();
  if (threadIdx.x == 0) atomicAdd(&acc[0], wsum[0] + wsum[1] + wsum[2] + wsum[3]);
}

// ---------------- K3: finalize loss ----------------
__global__ void k_fin(const double* __restrict__ acc, const int* __restrict__ cnt,
                      float* __restrict__ out) {
  double n_obj = fmax((double)cnt[1], 1.0);
  double n_noobj = fmax((double)(NCELL - cnt[0]), 1.0);
  double reg_loss = acc[2] / n_obj;
  double conf_loss = acc[1] / n_obj + acc[0] / n_noobj;
  double cls_loss = acc[3] / (n_obj * (double)NCLS);
  out[(size_t)NCELL * CHN] = (float)(reg_loss + 10.0*conf_loss + cls_loss);
}

extern "C" void kernel_launch(void* const* d_in, const int* in_sizes, int n_in,
                              void* d_out, int out_size, void* d_ws, size_t ws_size,
                              hipStream_t stream) {
  const float* in  = (const float*)d_in[0];
  const float* tgt = (const float*)d_in[1];
  float* out = (float*)d_out;
  double* acc = (double*)d_ws;                       // 4 doubles
  int* cnt = (int*)((char*)d_ws + 32);               // 2 ints
  unsigned* flags = (unsigned*)((char*)d_ws + 64);   // FLAG_WORDS words
  int nT = in_sizes[1] / 7;
  if (nT > NT_MAX) nT = NT_MAX;

  int nzw = 16 + FLAG_WORDS;                         // words to zero (acc+cnt+flags)
  hipLaunchKernelGGL(k_zero, dim3((nzw + 255)/256), dim3(256), 0, stream,
                     (unsigned*)d_ws, nzw);
  hipLaunchKernelGGL(k_prep, dim3(1), dim3(256), 0, stream, tgt, in, flags, acc, cnt, nT);
  hipLaunchKernelGGL(k_main, dim3(NB*NANC*NTILES), dim3(256), 0, stream, in, out, flags, acc);
  hipLaunchKernelGGL(k_fin, dim3(1), dim3(1), 0, stream, acc, cnt, out);
}

// Round 3
// 250.478 us; speedup vs baseline: 1.6031x; 1.3653x over previous
//
#include <hip/hip_runtime.h>
#include <math.h>

#define NCLS 80
#define NANC 18
#define NB 8
#define GG 76
#define SS (GG*GG)              // 5776
#define CHN (NCLS+6)            // 86
#define NCELL (NB*NANC*SS)      // 831744
#define FLAG_WORDS ((NCELL+31)/32)  // 25992
#define NT_MAX 240
#define TILE 64
#define NTILES ((SS+TILE-1)/TILE)   // 91 (last tile = 16 cells)
#define LSTR 65                 // LDS row stride in floats (bank-conflict-free reads)
#define PI_ 3.14159265358979323846

// ws layout (bytes): acc double[4]@0, cnt int[2]@32, win int[240]@64,
// meta int4[240]@1024, lm uint2[240]@4864, flags@6784
#define WS_WIN   64
#define WS_META  1024
#define WS_LM    4864
#define WS_FLAGS 6784
#define ZERO_WORDS ((WS_FLAGS + FLAG_WORDS*4)/4)   // 27688

// MASKED_ANCHORS: [w/8, h/8, angle] ; anchors outer, angles inner
__device__ __constant__ float d_ma[NANC][3] = {
  {1.5f, 2.0f, (float)(-PI_/3)}, {1.5f, 2.0f, (float)(-PI_/6)}, {1.5f, 2.0f, 0.0f},
  {1.5f, 2.0f, (float)(PI_/6)},  {1.5f, 2.0f, (float)(PI_/3)},  {1.5f, 2.0f, (float)(PI_/2)},
  {2.375f, 4.5f, (float)(-PI_/3)}, {2.375f, 4.5f, (float)(-PI_/6)}, {2.375f, 4.5f, 0.0f},
  {2.375f, 4.5f, (float)(PI_/6)},  {2.375f, 4.5f, (float)(PI_/3)},  {2.375f, 4.5f, (float)(PI_/2)},
  {5.0f, 3.5f, (float)(-PI_/3)}, {5.0f, 3.5f, (float)(-PI_/6)}, {5.0f, 3.5f, 0.0f},
  {5.0f, 3.5f, (float)(PI_/6)},  {5.0f, 3.5f, (float)(PI_/3)},  {5.0f, 3.5f, (float)(PI_/2)},
};

__device__ __forceinline__ float sigm(float x) { return 1.0f / (1.0f + expf(-x)); }
__device__ __forceinline__ float fsig(float x) {
  return __builtin_amdgcn_rcpf(1.0f + __expf(-x));
}

// ---------------- K0: zero workspace words ----------------
__global__ void k_zero(unsigned* __restrict__ w, int n) {
  int i = blockIdx.x * blockDim.x + threadIdx.x;
  if (i < n) w[i] = 0u;
}

// ---------------- K1: per-target decisions only (no `in` reads) ----------------
__global__ __launch_bounds__(256) void k_prep(const float* __restrict__ tgt,
                                              unsigned* __restrict__ flags,
                                              int* __restrict__ win,
                                              int4* __restrict__ meta,
                                              uint2* __restrict__ lmout,
                                              int* __restrict__ cnt, int nT) {
  __shared__ int s_key[NT_MAX], s_lab[NT_MAX];
  __shared__ int s_win[NT_MAX];
  __shared__ int s_zero;

  int t = threadIdx.x;
  if (t == 0) s_zero = 0;
  int bi = 0, gi = 0, gj = 0, bn = 0;
  unsigned cm = 0;
  if (t < nT) {
    float bf = tgt[t*7+0], lf = tgt[t*7+1];
    float gx = tgt[t*7+2] * (float)GG, gy = tgt[t*7+3] * (float)GG;
    float gw = tgt[t*7+4] * (float)GG, gh = tgt[t*7+5] * (float)GG;
    float ga = tgt[t*7+6];
    bi = (int)bf; gi = (int)gx; gj = (int)gy;
    int lab = (int)lf;
    float best = -1e30f;
    for (int a = 0; a < NANC; ++a) {
      float aw = d_ma[a][0], ah = d_ma[a][1], aa = d_ma[a][2];
      float inter = fminf(aw, gw) * fminf(ah, gh);
      float uni = aw*ah + 1e-16f + gw*gh - inter;
      float off = fabsf(aa - ga);
      float ar = inter / uni * fabsf(cosf(aa - ga));   // precise cosf: argmax stability
      if (ar > best) { best = ar; bn = a; }            // first-max wins (strict >)
      if (ar > 0.5f || (ar > 0.4f && off < (float)(PI_/12))) cm |= (1u << a);
    }
    s_key[t] = ((bi*NANC + bn)*GG + gj)*GG + gi;
    s_lab[t] = lab;
    s_win[t] = 0;
  }
  __syncthreads();

  if (t < nT) {
    // scatter noobj-zero bits: cond anchors + best anchor
    for (int a = 0; a < NANC; ++a) {
      if (((cm >> a) & 1u) || a == bn) {
        int cell = ((bi*NANC + a)*GG + gj)*GG + gi;
        unsigned bit = 1u << (cell & 31);
        unsigned old = atomicOr(&flags[cell >> 5], bit);
        if (!(old & bit)) atomicAdd(&s_zero, 1);
      }
    }
    // winner = last target (max index) with this cell key (numpy last-write-wins)
    int key = s_key[t];
    bool winner = true;
    for (int t2 = t + 1; t2 < nT; ++t2) if (s_key[t2] == key) { winner = false; break; }
    if (winner) {
      s_win[t] = 1;
      unsigned long long lm0 = 0, lm1 = 0;
      for (int t2 = 0; t2 < nT; ++t2) if (s_key[t2] == key) {
        int L = s_lab[t2];
        if (L < 64) lm0 |= 1ull << L; else lm1 |= 1ull << (L - 64);
      }
      // store label union as two 32-bit halves of each 64 (pack into uint2 pair via two words):
      // NCLS=80 -> lm0 (64 bits) + lm1 low 16. Pack: x=lo32(lm0), y=hi32(lm0), z..-> need 3 words.
      // Use lmout[t] = (lo32(lm0), hi32(lm0)) and stash lm1 low 16 in meta.w high bits? Keep simple:
      lmout[t] = make_uint2((unsigned)(lm0 & 0xffffffffull), (unsigned)(lm0 >> 32));
      meta[t] = make_int4(bi, bn, gi, gj | ((int)(lm1 & 0xffffu) << 16));
      win[t] = 1;
    } else {
      win[t] = 0;
    }
  }
  __syncthreads();
  if (t == 0) {
    int nw = 0;
    for (int i = 0; i < nT; ++i) nw += s_win[i];
    cnt[0] = s_zero; cnt[1] = nw;
  }
}

// ---------------- K1b: per-winner loss (one block per target) ----------------
__global__ __launch_bounds__(128) void k_cls(const float* __restrict__ tgt,
                                             const float* __restrict__ in,
                                             const int* __restrict__ win,
                                             const int4* __restrict__ meta,
                                             const uint2* __restrict__ lm,
                                             double* __restrict__ acc, int nT) {
  int t = blockIdx.x;
  if (t >= nT || !win[t]) return;
  int4 m = meta[t];
  int bi = m.x, bn = m.y, gi = m.z, gj = m.w & 0xffff;
  unsigned lmhi = ((unsigned)m.w) >> 16;           // classes 64..79
  uint2 l0 = lm[t];
  const float* base = in + ((size_t)(bi*NANC + bn)*CHN)*SS + (size_t)gj*GG + gi;
  int tid = threadIdx.x;

  // class BCE: lanes 0..79
  float csum = 0.0f;
  if (tid < NCLS) {
    float p = fsig(base[(size_t)(6 + tid)*SS]);
    float pl = fminf(fmaxf(p, 1e-7f), 1.0f - 1e-7f);
    bool tc;
    if (tid < 32)      tc = (l0.x >> tid) & 1u;
    else if (tid < 64) tc = (l0.y >> (tid - 32)) & 1u;
    else               tc = (lmhi >> (tid - 64)) & 1u;
    csum = tc ? -__logf(pl) : -__logf(1.0f - pl);
  }
  for (int off = 32; off; off >>= 1) csum += __shfl_down(csum, off);
  if ((tid & 63) == 0) atomicAdd(&acc[3], (double)csum);

  // scalar winner terms: one thread
  if (tid == 96) {
    float gx = tgt[t*7+2] * (float)GG, gyv = tgt[t*7+3] * (float)GG;
    float gw = tgt[t*7+4] * (float)GG, gh = tgt[t*7+5] * (float)GG;
    float ga = tgt[t*7+6];
    float rx = base[0], ry = base[(size_t)SS], rw = base[2*(size_t)SS],
          rh = base[3*(size_t)SS], ra = base[4*(size_t)SS], rcf = base[5*(size_t)SS];
    float aw = d_ma[bn][0], ah = d_ma[bn][1], aa = d_ma[bn][2];
    float px = sigm(rx)*1.05f - 0.025f + (float)gi;
    float py = sigm(ry)*1.05f - 0.025f + (float)gj;
    float pw = expf(rw)*aw, ph = expf(rh)*ah;
    float pang = ra + aa;
    float p1x = px - pw*0.5f, p1y = py - ph*0.5f, p2x = px + pw*0.5f, p2y = py + ph*0.5f;
    float t1x = gx - gw*0.5f, t1y = gyv - gh*0.5f, t2x = gx + gw*0.5f, t2y = gyv + gh*0.5f;
    float w1 = p2x - p1x, h1 = p2y - p1y, w2 = t2x - t1x, h2 = t2y - t1y;
    float area1 = w1*h1, area2 = w2*h2;
    float c1x = (p1x+p2x)*0.5f, c1y = (p1y+p2y)*0.5f, c2x = (t1x+t2x)*0.5f, c2y = (t1y+t2y)*0.5f;
    float ix = fmaxf(fminf(p2x,t2x) - fmaxf(p1x,t1x), 0.0f);
    float iy = fmaxf(fminf(p2y,t2y) - fmaxf(p1y,t1y), 0.0f);
    float inter_area = ix*iy;
    float dcx = c2x - c1x, dcy = c2y - c1y;
    float inter_diag = dcx*dcx + dcy*dcy;
    float ox = fmaxf(fmaxf(p2x,t2x) - fminf(p1x,t1x), 0.0f);
    float oy = fmaxf(fmaxf(p2y,t2y) - fminf(p1y,t1y), 0.0f);
    float outer_diag = ox*ox + oy*oy;
    float uni = area1 + area2 - inter_area;
    float u = inter_diag / outer_diag;
    float iou = inter_area / uni;
    float da = atanf(w2/h2) - atanf(w1/h1);
    float v = (float)(4.0/(PI_*PI_)) * da * da;
    float alpha = v / (1.0f - iou + v);
    float ciou = fminf(fmaxf(iou - (u + alpha*v), -1.0f), 1.0f);
    float skew_iou = iou * fabsf(cosf(pang - ga));
    float skew = expf(1.0f - skew_iou) - 1.0f;
    float bscale = 2.0f - gw*gh/369664.0f;   // (8*76)^2
    float ciou_t = bscale * (1.0f - ciou);
    float ta = ga - aa;
    float d = fabsf(ra - ta);
    float sl1 = (d < 1.0f) ? 0.5f*d*d : d - 0.5f;
    float reg = sl1 + ciou_t;
    atomicAdd(&acc[2], (double)(reg * (skew / reg)));
    float pc = sigm(rcf);
    float pcl = fminf(fmaxf(pc, 1e-7f), 1.0f - 1e-7f);
    float om = 1.0f - pc;
    atomicAdd(&acc[1], (double)(-logf(pcl) * 0.25f * om * om));
  }
}

// ---------------- K2: transpose/decode + noobj focal ----------------
// Phase 1: stage 86ch x count cells via float4 loads (MLP=6/thread).
// Phase 2: wave 0 decodes box ch0..4 in-place in LDS + conf focal (flags).
// Phase 3: branch-free float2 store stream over all 86 channels.
__global__ __launch_bounds__(256) void k_main(const float* __restrict__ in,
                                              float* __restrict__ out,
                                              const unsigned* __restrict__ flags,
                                              double* __restrict__ acc) {
  __shared__ float lds[CHN * LSTR];
  int blk = blockIdx.x;
  int tile = blk % NTILES;
  int ba = blk / NTILES;
  int a = ba % NANC, b = ba / NANC;
  int s0 = tile * TILE;
  int count = min(TILE, SS - s0);          // 64 or 16
  int cnt4 = count >> 2;                   // 16 or 4 (pow2)
  int sh = (count == TILE) ? 4 : 2;
  int tot4 = CHN * cnt4;

  const float* inb = in + ((size_t)(b*NANC + a)*CHN)*SS + s0;

  // Phase 1: stage
  float4 r[6];
  #pragma unroll
  for (int k = 0; k < 6; ++k) {
    int i = threadIdx.x + k*256;
    if (i < tot4) {
      int c = i >> sh, s4 = i & (cnt4 - 1);
      r[k] = *(const float4*)(inb + (size_t)c*SS + 4*s4);
    }
  }
  #pragma unroll
  for (int k = 0; k < 6; ++k) {
    int i = threadIdx.x + k*256;
    if (i < tot4) {
      int c = i >> sh, s4 = i & (cnt4 - 1);
      float* p = &lds[c*LSTR + 4*s4];
      p[0] = r[k].x; p[1] = r[k].y; p[2] = r[k].z; p[3] = r[k].w;
    }
  }
  __syncthreads();

  // Phase 2: box decode in-place + conf focal (wave 0 only)
  if (threadIdx.x < 64) {
    int s = threadIdx.x;
    double fl = 0.0;
    if (s < count) {
      int spos = s0 + s;
      int gy = spos / GG, gx = spos - gy*GG;
      float aw = d_ma[a][0], ah = d_ma[a][1], aa = d_ma[a][2];
      lds[0*LSTR+s] = (fsig(lds[0*LSTR+s])*1.05f - 0.025f + (float)gx) * 8.0f;
      lds[1*LSTR+s] = (fsig(lds[1*LSTR+s])*1.05f - 0.025f + (float)gy) * 8.0f;
      lds[2*LSTR+s] = __expf(lds[2*LSTR+s]) * aw * 8.0f;
      lds[3*LSTR+s] = __expf(lds[3*LSTR+s]) * ah * 8.0f;
      lds[4*LSTR+s] = lds[4*LSTR+s] + aa;
      float p = fsig(lds[5*LSTR+s]);
      int cell = (b*NANC + a)*SS + spos;
      if (!((flags[cell >> 5] >> (cell & 31)) & 1u)) {
        float pcl = fminf(fmaxf(p, 1e-7f), 1.0f - 1e-7f);
        fl = (double)(-__logf(1.0f - pcl) * 0.75f * p * p);
      }
    }
    for (int off = 32; off; off >>= 1) fl += __shfl_down(fl, off);
    if (threadIdx.x == 0 && fl != 0.0) atomicAdd(&acc[0], fl);
  }
  __syncthreads();

  // Phase 3: branch-free float2 store stream. out offset of pair o2 = o2*8 bytes.
  int np = count * (CHN/2);                // 2752 or 688
  float2* outb2 = (float2*)(out + ((size_t)(b*NANC + a)*SS + s0)*CHN);
  for (int o2 = threadIdx.x; o2 < np; o2 += 256) {
    int s = o2 / (CHN/2);                  // magic-mul (43)
    int h = o2 - s*(CHN/2);
    float v0 = lds[(2*h    )*LSTR + s];
    float v1 = lds[(2*h + 1)*LSTR + s];
    float r0 = (h < 3) ? v0 : fsig(v0);    // c0=2h   in {0,2,4} -> pass-through
    float r1 = (h < 2) ? v1 : fsig(v1);    // c1=2h+1 in {1,3}   -> pass-through; c1=5 -> sigmoid
    outb2[o2] = make_float2(r0, r1);
  }
}

// ---------------- K3: finalize loss ----------------
__global__ void k_fin(const double* __restrict__ acc, const int* __restrict__ cnt,
                      float* __restrict__ out) {
  double n_obj = fmax((double)cnt[1], 1.0);
  double n_noobj = fmax((double)(NCELL - cnt[0]), 1.0);
  double reg_loss = acc[2] / n_obj;
  double conf_loss = acc[1] / n_obj + acc[0] / n_noobj;
  double cls_loss = acc[3] / (n_obj * (double)NCLS);
  out[(size_t)NCELL * CHN] = (float)(reg_loss + 10.0*conf_loss + cls_loss);
}

extern "C" void kernel_launch(void* const* d_in, const int* in_sizes, int n_in,
                              void* d_out, int out_size, void* d_ws, size_t ws_size,
                              hipStream_t stream) {
  const float* in  = (const float*)d_in[0];
  const float* tgt = (const float*)d_in[1];
  float* out = (float*)d_out;
  double* acc = (double*)d_ws;
  int* cnt = (int*)((char*)d_ws + 32);
  int* win = (int*)((char*)d_ws + WS_WIN);
  int4* meta = (int4*)((char*)d_ws + WS_META);
  uint2* lm = (uint2*)((char*)d_ws + WS_LM);
  unsigned* flags = (unsigned*)((char*)d_ws + WS_FLAGS);
  int nT = in_sizes[1] / 7;
  if (nT > NT_MAX) nT = NT_MAX;

  hipLaunchKernelGGL(k_zero, dim3((ZERO_WORDS + 255)/256), dim3(256), 0, stream,
                     (unsigned*)d_ws, ZERO_WORDS);
  hipLaunchKernelGGL(k_prep, dim3(1), dim3(256), 0, stream, tgt, flags, win, meta, lm, cnt, nT);
  hipLaunchKernelGGL(k_cls, dim3(nT), dim3(128), 0, stream, tgt, in, win, meta, lm, acc, nT);
  hipLaunchKernelGGL(k_main, dim3(NB*NANC*NTILES), dim3(256), 0, stream, in, out, flags, acc);
  hipLaunchKernelGGL(k_fin, dim3(1), dim3(1), 0, stream, acc, cnt, out);
}

// Round 4
// 208.775 us; speedup vs baseline: 1.9233x; 1.1998x over previous
//
#include <hip/hip_runtime.h>
#include <math.h>

#define NCLS 80
#define NANC 18
#define NB 8
#define GG 76
#define SS (GG*GG)              // 5776
#define CHN (NCLS+6)            // 86
#define NCELL (NB*NANC*SS)      // 831744
#define FLAG_WORDS ((NCELL+31)/32)  // 25992
#define NT_MAX 240
#define TILE 76                 // one grid row per tile
#define LSTR 77                 // LDS row stride (floats)
#define TPB 4                   // tiles per block (pipelined)
#define TGRP (GG/TPB)           // 19 tile-groups per plane
#define NLOAD 7                 // ceil(86*19 float4 / 256 threads)
#define TOT4 (CHN*(TILE/4))     // 1634 float4 per tile
#define NCONF4 (NCELL/4)        // 207936
#define NCONFBLK ((NCONF4+255)/256) // 813
#define PI_ 3.14159265358979323846

// ws layout (bytes): acc double[4]@0, cnt int[2]@32, win int[240]@64,
// meta int4[240]@1024, lm uint2[240]@4864, flags@6784
#define WS_WIN   64
#define WS_META  1024
#define WS_LM    4864
#define WS_FLAGS 6784
#define ZERO_WORDS ((WS_FLAGS + FLAG_WORDS*4)/4)

__device__ __constant__ float d_ma[NANC][3] = {
  {1.5f, 2.0f, (float)(-PI_/3)}, {1.5f, 2.0f, (float)(-PI_/6)}, {1.5f, 2.0f, 0.0f},
  {1.5f, 2.0f, (float)(PI_/6)},  {1.5f, 2.0f, (float)(PI_/3)},  {1.5f, 2.0f, (float)(PI_/2)},
  {2.375f, 4.5f, (float)(-PI_/3)}, {2.375f, 4.5f, (float)(-PI_/6)}, {2.375f, 4.5f, 0.0f},
  {2.375f, 4.5f, (float)(PI_/6)},  {2.375f, 4.5f, (float)(PI_/3)},  {2.375f, 4.5f, (float)(PI_/2)},
  {5.0f, 3.5f, (float)(-PI_/3)}, {5.0f, 3.5f, (float)(-PI_/6)}, {5.0f, 3.5f, 0.0f},
  {5.0f, 3.5f, (float)(PI_/6)},  {5.0f, 3.5f, (float)(PI_/3)},  {5.0f, 3.5f, (float)(PI_/2)},
};

__device__ __forceinline__ float sigm(float x) { return 1.0f / (1.0f + expf(-x)); }
__device__ __forceinline__ float fsig(float x) {
  return __builtin_amdgcn_rcpf(1.0f + __expf(-x));
}

// ---------------- K0: zero workspace words ----------------
__global__ void k_zero(unsigned* __restrict__ w, int n) {
  int i = blockIdx.x * blockDim.x + threadIdx.x;
  if (i < n) w[i] = 0u;
}

// ---------------- K1: per-target decisions (no `in` reads) ----------------
__global__ __launch_bounds__(256) void k_prep(const float* __restrict__ tgt,
                                              unsigned* __restrict__ flags,
                                              int* __restrict__ win,
                                              int4* __restrict__ meta,
                                              uint2* __restrict__ lmout,
                                              int* __restrict__ cnt, int nT) {
  __shared__ int s_key[NT_MAX], s_lab[NT_MAX];
  __shared__ int s_win[NT_MAX];
  __shared__ int s_zero;

  int t = threadIdx.x;
  if (t == 0) s_zero = 0;
  int bi = 0, gi = 0, gj = 0, bn = 0;
  unsigned cm = 0;
  if (t < nT) {
    float bf = tgt[t*7+0], lf = tgt[t*7+1];
    float gx = tgt[t*7+2] * (float)GG, gy = tgt[t*7+3] * (float)GG;
    float gw = tgt[t*7+4] * (float)GG, gh = tgt[t*7+5] * (float)GG;
    float ga = tgt[t*7+6];
    bi = (int)bf; gi = (int)gx; gj = (int)gy;
    int lab = (int)lf;
    float best = -1e30f;
    for (int a = 0; a < NANC; ++a) {
      float aw = d_ma[a][0], ah = d_ma[a][1], aa = d_ma[a][2];
      float inter = fminf(aw, gw) * fminf(ah, gh);
      float uni = aw*ah + 1e-16f + gw*gh - inter;
      float off = fabsf(aa - ga);
      float ar = inter / uni * fabsf(cosf(aa - ga));   // precise cosf: argmax stability
      if (ar > best) { best = ar; bn = a; }            // first-max wins (strict >)
      if (ar > 0.5f || (ar > 0.4f && off < (float)(PI_/12))) cm |= (1u << a);
    }
    s_key[t] = ((bi*NANC + bn)*GG + gj)*GG + gi;
    s_lab[t] = lab;
    s_win[t] = 0;
  }
  __syncthreads();

  if (t < nT) {
    for (int a = 0; a < NANC; ++a) {
      if (((cm >> a) & 1u) || a == bn) {
        int cell = ((bi*NANC + a)*GG + gj)*GG + gi;
        unsigned bit = 1u << (cell & 31);
        unsigned old = atomicOr(&flags[cell >> 5], bit);
        if (!(old & bit)) atomicAdd(&s_zero, 1);
      }
    }
    // winner = last target (max index) with this cell key (numpy last-write-wins)
    int key = s_key[t];
    bool winner = true;
    for (int t2 = t + 1; t2 < nT; ++t2) if (s_key[t2] == key) { winner = false; break; }
    if (winner) {
      s_win[t] = 1;
      unsigned long long lm0 = 0, lm1 = 0;
      for (int t2 = 0; t2 < nT; ++t2) if (s_key[t2] == key) {
        int L = s_lab[t2];
        if (L < 64) lm0 |= 1ull << L; else lm1 |= 1ull << (L - 64);
      }
      lmout[t] = make_uint2((unsigned)(lm0 & 0xffffffffull), (unsigned)(lm0 >> 32));
      meta[t] = make_int4(bi, bn, gi, gj | ((int)(lm1 & 0xffffu) << 16));
      win[t] = 1;
    } else {
      win[t] = 0;
    }
  }
  __syncthreads();
  if (t == 0) {
    int nw = 0;
    for (int i = 0; i < nT; ++i) nw += s_win[i];
    cnt[0] = s_zero; cnt[1] = nw;
  }
}

// ---------------- K2: fused loss kernel ----------------
// blocks [0, nT): per-winner cls/reg/conf(t=1) terms.
// blocks [nT, nT+NCONFBLK): noobj focal over the conf-channel plane (flag-gated).
__global__ __launch_bounds__(256) void k_loss(const float* __restrict__ tgt,
                                              const float* __restrict__ in,
                                              const int* __restrict__ win,
                                              const int4* __restrict__ meta,
                                              const uint2* __restrict__ lm,
                                              const unsigned* __restrict__ flags,
                                              double* __restrict__ acc, int nT) {
  int blk = blockIdx.x;
  int tid = threadIdx.x;

  if (blk < nT) {
    int t = blk;
    if (!win[t]) return;
    int4 m = meta[t];
    int bi = m.x, bn = m.y, gi = m.z, gj = m.w & 0xffff;
    unsigned lmhi = ((unsigned)m.w) >> 16;
    uint2 l0 = lm[t];
    const float* base = in + ((size_t)(bi*NANC + bn)*CHN)*SS + (size_t)gj*GG + gi;

    float csum = 0.0f;
    if (tid < NCLS) {
      float p = fsig(base[(size_t)(6 + tid)*SS]);
      float pl = fminf(fmaxf(p, 1e-7f), 1.0f - 1e-7f);
      bool tc;
      if (tid < 32)      tc = (l0.x >> tid) & 1u;
      else if (tid < 64) tc = (l0.y >> (tid - 32)) & 1u;
      else               tc = (lmhi >> (tid - 64)) & 1u;
      csum = tc ? -__logf(pl) : -__logf(1.0f - pl);
    }
    for (int off = 32; off; off >>= 1) csum += __shfl_down(csum, off);
    if ((tid & 63) == 0 && tid < 128) atomicAdd(&acc[3], (double)csum);

    if (tid == 128) {
      float gx = tgt[t*7+2] * (float)GG, gyv = tgt[t*7+3] * (float)GG;
      float gw = tgt[t*7+4] * (float)GG, gh = tgt[t*7+5] * (float)GG;
      float ga = tgt[t*7+6];
      float rx = base[0], ry = base[(size_t)SS], rw = base[2*(size_t)SS],
            rh = base[3*(size_t)SS], ra = base[4*(size_t)SS], rcf = base[5*(size_t)SS];
      float aw = d_ma[bn][0], ah = d_ma[bn][1], aa = d_ma[bn][2];
      float px = sigm(rx)*1.05f - 0.025f + (float)gi;
      float py = sigm(ry)*1.05f - 0.025f + (float)gj;
      float pw = expf(rw)*aw, ph = expf(rh)*ah;
      float pang = ra + aa;
      float p1x = px - pw*0.5f, p1y = py - ph*0.5f, p2x = px + pw*0.5f, p2y = py + ph*0.5f;
      float t1x = gx - gw*0.5f, t1y = gyv - gh*0.5f, t2x = gx + gw*0.5f, t2y = gyv + gh*0.5f;
      float w1 = p2x - p1x, h1 = p2y - p1y, w2 = t2x - t1x, h2 = t2y - t1y;
      float area1 = w1*h1, area2 = w2*h2;
      float c1x = (p1x+p2x)*0.5f, c1y = (p1y+p2y)*0.5f, c2x = (t1x+t2x)*0.5f, c2y = (t1y+t2y)*0.5f;
      float ix = fmaxf(fminf(p2x,t2x) - fmaxf(p1x,t1x), 0.0f);
      float iy = fmaxf(fminf(p2y,t2y) - fmaxf(p1y,t1y), 0.0f);
      float inter_area = ix*iy;
      float dcx = c2x - c1x, dcy = c2y - c1y;
      float inter_diag = dcx*dcx + dcy*dcy;
      float ox = fmaxf(fmaxf(p2x,t2x) - fminf(p1x,t1x), 0.0f);
      float oy = fmaxf(fmaxf(p2y,t2y) - fminf(p1y,t1y), 0.0f);
      float outer_diag = ox*ox + oy*oy;
      float uni = area1 + area2 - inter_area;
      float u = inter_diag / outer_diag;
      float iou = inter_area / uni;
      float da = atanf(w2/h2) - atanf(w1/h1);
      float v = (float)(4.0/(PI_*PI_)) * da * da;
      float alpha = v / (1.0f - iou + v);
      float ciou = fminf(fmaxf(iou - (u + alpha*v), -1.0f), 1.0f);
      float skew_iou = iou * fabsf(cosf(pang - ga));
      float skew = expf(1.0f - skew_iou) - 1.0f;
      float bscale = 2.0f - gw*gh/369664.0f;   // (8*76)^2
      float ciou_t = bscale * (1.0f - ciou);
      float ta = ga - aa;
      float d = fabsf(ra - ta);
      float sl1 = (d < 1.0f) ? 0.5f*d*d : d - 0.5f;
      float reg = sl1 + ciou_t;
      atomicAdd(&acc[2], (double)(reg * (skew / reg)));
      float pc = sigm(rcf);
      float pcl = fminf(fmaxf(pc, 1e-7f), 1.0f - 1e-7f);
      float om = 1.0f - pc;
      atomicAdd(&acc[1], (double)(-logf(pcl) * 0.25f * om * om));
    }
    return;
  }

  // ---- conf part: noobj focal over all cells (channel 5), flag-gated ----
  __shared__ double wsum[4];
  int j = (blk - nT)*256 + tid;
  double fl = 0.0;
  if (j < NCONF4) {
    int ba = j / (SS/4);                 // plane index (b*NANC+a)
    int q  = j - ba*(SS/4);
    int spos = 4*q;
    const float4 v4 = *(const float4*)(in + (size_t)ba*CHN*SS + 5*(size_t)SS + spos);
    int cell0 = ba*SS + spos;
    unsigned word = flags[cell0 >> 5];
    int bbit = cell0 & 31;               // multiple of 4, bits bbit..bbit+3 in same word
    float pv[4] = {v4.x, v4.y, v4.z, v4.w};
    #pragma unroll
    for (int e = 0; e < 4; ++e) {
      if (!((word >> (bbit + e)) & 1u)) {
        float p = fsig(pv[e]);
        float pcl = fminf(fmaxf(p, 1e-7f), 1.0f - 1e-7f);
        fl += (double)(-__logf(1.0f - pcl) * 0.75f * p * p);
      }
    }
  }
  int lane = tid & 63, wid = tid >> 6;
  for (int off = 32; off; off >>= 1) fl += __shfl_down(fl, off);
  if (lane == 0) wsum[wid] = fl;
  __syncthreads();
  if (tid == 0) {
    double s = wsum[0] + wsum[1] + wsum[2] + wsum[3];
    if (s != 0.0) atomicAdd(&acc[0], s);
  }
}

// ---------------- K3: pure transpose/decode, 4 row-tiles per block, pipelined ----------------
__global__ __launch_bounds__(256) void k_main(const float* __restrict__ in,
                                              float* __restrict__ out) {
  __shared__ float lds[CHN * LSTR];      // 26488 B
  int blk = blockIdx.x;
  int tgrp = blk % TGRP;
  int ba = blk / TGRP;
  int a = ba % NANC;
  float aw8 = d_ma[a][0] * 8.0f, ah8 = d_ma[a][1] * 8.0f, aa = d_ma[a][2];

  const float* plane_in = in + (size_t)ba * CHN * SS;
  float* plane_out = out + (size_t)ba * SS * CHN;

  int tile0 = tgrp * TPB;
  float4 r[NLOAD];

  // prologue: load tile0
  {
    const float* tin = plane_in + tile0 * TILE;
    #pragma unroll
    for (int k = 0; k < NLOAD; ++k) {
      int i = threadIdx.x + k*256;
      if (i < TOT4) {
        int c = i / (TILE/4), s4 = i - c*(TILE/4);
        r[k] = *(const float4*)(tin + (size_t)c*SS + 4*s4);
      }
    }
  }

  for (int tt = 0; tt < TPB; ++tt) {
    int tile = tile0 + tt;
    __syncthreads();                     // prior store-loop LDS reads done
    #pragma unroll
    for (int k = 0; k < NLOAD; ++k) {
      int i = threadIdx.x + k*256;
      if (i < TOT4) {
        int c = i / (TILE/4), s4 = i - c*(TILE/4);
        float* p = &lds[c*LSTR + 4*s4];
        p[0] = r[k].x; p[1] = r[k].y; p[2] = r[k].z; p[3] = r[k].w;
      }
    }
    __syncthreads();
    if (tt + 1 < TPB) {                  // prefetch next tile into regs
      const float* tin = plane_in + (tile + 1) * TILE;
      #pragma unroll
      for (int k = 0; k < NLOAD; ++k) {
        int i = threadIdx.x + k*256;
        if (i < TOT4) {
          int c = i / (TILE/4), s4 = i - c*(TILE/4);
          r[k] = *(const float4*)(tin + (size_t)c*SS + 4*s4);
        }
      }
    }
    // store stream: 76 cells x 43 float2; gx = s, gy = tile
    float gyf = (float)tile;
    float2* outb2 = (float2*)(plane_out + (size_t)tile * TILE * CHN);
    for (int o2 = threadIdx.x; o2 < TILE*(CHN/2); o2 += 256) {
      int s = o2 / (CHN/2);
      int h = o2 - s*(CHN/2);
      float v0 = lds[(2*h    )*LSTR + s];
      float v1 = lds[(2*h + 1)*LSTR + s];
      float r0, r1;
      if (h >= 3)      { r0 = fsig(v0); r1 = fsig(v1); }
      else if (h == 0) { r0 = (fsig(v0)*1.05f - 0.025f + (float)s)*8.0f;
                         r1 = (fsig(v1)*1.05f - 0.025f + gyf)*8.0f; }
      else if (h == 1) { r0 = __expf(v0)*aw8; r1 = __expf(v1)*ah8; }
      else             { r0 = v0 + aa; r1 = fsig(v1); }
      outb2[o2] = make_float2(r0, r1);
    }
  }
}

// ---------------- K4: finalize loss ----------------
__global__ void k_fin(const double* __restrict__ acc, const int* __restrict__ cnt,
                      float* __restrict__ out) {
  double n_obj = fmax((double)cnt[1], 1.0);
  double n_noobj = fmax((double)(NCELL - cnt[0]), 1.0);
  double reg_loss = acc[2] / n_obj;
  double conf_loss = acc[1] / n_obj + acc[0] / n_noobj;
  double cls_loss = acc[3] / (n_obj * (double)NCLS);
  out[(size_t)NCELL * CHN] = (float)(reg_loss + 10.0*conf_loss + cls_loss);
}

extern "C" void kernel_launch(void* const* d_in, const int* in_sizes, int n_in,
                              void* d_out, int out_size, void* d_ws, size_t ws_size,
                              hipStream_t stream) {
  const float* in  = (const float*)d_in[0];
  const float* tgt = (const float*)d_in[1];
  float* out = (float*)d_out;
  double* acc = (double*)d_ws;
  int* cnt = (int*)((char*)d_ws + 32);
  int* win = (int*)((char*)d_ws + WS_WIN);
  int4* meta = (int4*)((char*)d_ws + WS_META);
  uint2* lm = (uint2*)((char*)d_ws + WS_LM);
  unsigned* flags = (unsigned*)((char*)d_ws + WS_FLAGS);
  int nT = in_sizes[1] / 7;
  if (nT > NT_MAX) nT = NT_MAX;

  hipLaunchKernelGGL(k_zero, dim3((ZERO_WORDS + 255)/256), dim3(256), 0, stream,
                     (unsigned*)d_ws, ZERO_WORDS);
  hipLaunchKernelGGL(k_prep, dim3(1), dim3(256), 0, stream, tgt, flags, win, meta, lm, cnt, nT);
  hipLaunchKernelGGL(k_loss, dim3(nT + NCONFBLK), dim3(256), 0, stream,
                     tgt, in, win, meta, lm, flags, acc, nT);
  hipLaunchKernelGGL(k_fin, dim3(1), dim3(1), 0, stream, acc, cnt, out);
  hipLaunchKernelGGL(k_main, dim3(NB*NANC*TGRP), dim3(256), 0, stream, in, out);
}